// Round 8
// baseline (169.413 us; speedup 1.0000x reference)
//
#include <hip/hip_runtime.h>
#include <math.h>

#define BATCH   4
#define N1      2048
#define N2      8192
#define F       256
#define NTOT1   (BATCH * N1)    // 8192
#define NTOT2   (BATCH * N2)    // 32768
#define BN_EPS  1e-5f

// kNN acceleration grid: 6x6x6 cells over [0,1)^3, ~9.5 pts/cell
#define GR      6
#define NC      216             // GR^3
#define NCP     (NC + 1)        // 217
#define GH      (1.0f / 6.0f)

typedef __attribute__((ext_vector_type(8))) short bf16x8;
typedef __attribute__((ext_vector_type(8))) unsigned short u16x8;
typedef __attribute__((ext_vector_type(4))) float f32x4;

// ---------------- helpers ----------------------------------------------------
__device__ __forceinline__ unsigned short f2bf(float f) {   // RNE f32->bf16
    unsigned u = __float_as_uint(f);
    unsigned r = (u + 0x7fffu + ((u >> 16) & 1u)) >> 16;
    return (unsigned short)r;
}
__device__ __forceinline__ float bflo(unsigned u) {         // low bf16 of pair
    return __uint_as_float(u << 16);
}
__device__ __forceinline__ float bfhi(unsigned u) {         // high bf16 of pair
    return __uint_as_float(u & 0xffff0000u);
}
__device__ __forceinline__ void async16(const void* g, void* l) {
    __builtin_amdgcn_global_load_lds(
        (const __attribute__((address_space(1))) unsigned int*)g,
        (__attribute__((address_space(3))) unsigned int*)l, 16, 0, 0);
}

// branchless top-3 insert, med3 form. Invariant d0<=d1<=d2.
// Strict < == first-occurrence tie-break.
__device__ __forceinline__ void ins3m(float d, int j,
                                      float& d0, float& d1, float& d2,
                                      int& j0, int& j1, int& j2) {
    const bool c0 = d < d0;
    const bool c1 = d < d1;
    const bool c2 = d < d2;
    const float nd1 = __builtin_amdgcn_fmed3f(d, d0, d1);
    const float nd2 = __builtin_amdgcn_fmed3f(d, d1, d2);
    d0 = fminf(d, d0);
    d1 = nd1;
    d2 = nd2;
    j2 = c1 ? j1 : (c2 ? j : j2);
    j1 = c0 ? j0 : (c1 ? j : j1);
    j0 = c0 ? j  : j0;
}

__device__ __forceinline__ int clamp6(int c) { return c < 0 ? 0 : (c > 5 ? 5 : c); }
__device__ __forceinline__ int cell_of(float x, float y, float z) {
    const int cx = clamp6((int)(x * 6.0f));
    const int cy = clamp6((int)(y * 6.0f));
    const int cz = clamp6((int)(z * 6.0f));
    return (cz * 6 + cy) * 6 + cx;
}

// =============================================================================
// Dispatch 1: prep — W->bf16 transposed + zero stats. grid = 33 blocks.
// =============================================================================
__global__ __launch_bounds__(256) void prep_kernel(const float* __restrict__ W1,
                                                   const float* __restrict__ W2,
                                                   unsigned short* __restrict__ Wt1,
                                                   unsigned short* __restrict__ Wt2,
                                                   float* __restrict__ sums) {
    const int bx = blockIdx.x;
    const int t  = threadIdx.x;

    if (bx < 32) {                        // W transpose+convert
        __shared__ float tile[64][65];
        const bool second = bx >= 16;
        const int bl = second ? bx - 16 : bx;
        const float* W = second ? W2 : W1;
        unsigned short* Wt = second ? Wt2 : Wt1;
        const int gx0 = (bl & 3) * 64;    // n block
        const int gy0 = (bl >> 2) * 64;   // k block
        const int tx = t & 63;
        const int ty = t >> 6;
        #pragma unroll
        for (int j = 0; j < 16; ++j) {
            const int row = ty * 16 + j;
            tile[row][tx] = W[(size_t)(gy0 + row) * 256 + gx0 + tx];
        }
        __syncthreads();
        #pragma unroll
        for (int j = 0; j < 16; ++j) {
            const int row = ty * 16 + j;
            Wt[(size_t)(gx0 + row) * 256 + gy0 + tx] = f2bf(tile[tx][row]);
        }
    } else {                              // zero sums (before gemm's atomics)
        #pragma unroll
        for (int i = 0; i < 4; ++i) sums[t + 256 * i] = 0.0f;
    }
}

// =============================================================================
// Dispatch 2: both GEMMs (bx<640) + CONCURRENT binning blocks (bx 640..647).
// GEMM restructure (single variable vs R7): double-buffered Bs via async16 +
// software-pipelined reg-staged A (global f32 -> reg -> f2bf -> MFMA fragment,
// no A-LDS), ONE __syncthreads per K-step. Next-step loads issued at the TOP
// of each step so the barrier's vmcnt(0) drain sits after the full compute
// phase (cvt + ds_read + 16 MFMA) of cover. MFMA inputs bit-identical to R7.
// =============================================================================
__global__ __launch_bounds__(256) void gemm_mfma_kernel(const float* __restrict__ f1,
                                                        const float* __restrict__ f2,
                                                        const unsigned short* __restrict__ Wt1,
                                                        const unsigned short* __restrict__ Wt2,
                                                        const float* __restrict__ b1,
                                                        const float* __restrict__ b2,
                                                        const float* __restrict__ p1,
                                                        const float* __restrict__ p2,
                                                        unsigned short* __restrict__ h1b,
                                                        unsigned short* __restrict__ h2b,
                                                        float* __restrict__ sums,
                                                        float4* __restrict__ gridPts,
                                                        int* __restrict__ cellStart,
                                                        int* __restrict__ qSorted,
                                                        int* __restrict__ qCellStart) {
    __shared__ unsigned short Bs[2][128 * 32];   // 2 x 8 KB (double-buffered)

    const int bx = blockIdx.x;
    const int t  = threadIdx.x;

    if (bx >= 640) {                      // ---- binning blocks (for fused) ----
        __shared__ int cnt[NC];
        __shared__ int ofs[NCP];
        __shared__ unsigned char cellb[N2];   // 8 KB query-cell cache
        const int bb = bx - 640;
        if (bb < 4) {                     // bin points of batch bb into 6^3 grid
            const int b = bb;
            if (t < NC) cnt[t] = 0;
            __syncthreads();
            int   myc[8];
            float mx[8], my[8], mz[8];
            #pragma unroll
            for (int r = 0; r < 8; ++r) {
                const int i = r * 256 + t;
                const size_t base = (size_t)(b * N1 + i) * 3;
                mx[r] = p1[base]; my[r] = p1[base + 1]; mz[r] = p1[base + 2];
                myc[r] = cell_of(mx[r], my[r], mz[r]);
                atomicAdd(&cnt[myc[r]], 1);
            }
            __syncthreads();
            if (t <= NC) ofs[t] = (t == 0) ? 0 : cnt[t - 1];   // exclusive init
            __syncthreads();
            for (int dd = 1; dd < NCP; dd <<= 1) {             // Hillis-Steele
                int v = 0;
                if (t <= NC && t >= dd) v = ofs[t - dd];
                __syncthreads();
                if (t <= NC && t >= dd) ofs[t] += v;
                __syncthreads();
            }
            if (t < NC) cnt[t] = ofs[t];                       // cursors
            __syncthreads();
            #pragma unroll
            for (int r = 0; r < 8; ++r) {
                const int i = r * 256 + t;
                const int pos = atomicAdd(&cnt[myc[r]], 1);
                float4 rec;
                rec.x = mx[r]; rec.y = my[r]; rec.z = mz[r];
                rec.w = __int_as_float(i);                     // in-batch idx
                gridPts[(size_t)b * N1 + pos] = rec;
            }
            if (t <= NC) cellStart[b * NCP + t] = ofs[t];
        } else {                          // bin queries of batch bb-4
            const int b = bb - 4;
            if (t < NC) cnt[t] = 0;
            __syncthreads();
            for (int r = 0; r < 32; ++r) {
                const int i = r * 256 + t;
                const size_t base = (size_t)(b * N2 + i) * 3;
                const int c = cell_of(p2[base], p2[base + 1], p2[base + 2]);
                cellb[i] = (unsigned char)c;
                atomicAdd(&cnt[c], 1);
            }
            __syncthreads();
            if (t <= NC) ofs[t] = (t == 0) ? 0 : cnt[t - 1];
            __syncthreads();
            for (int dd = 1; dd < NCP; dd <<= 1) {
                int v = 0;
                if (t <= NC && t >= dd) v = ofs[t - dd];
                __syncthreads();
                if (t <= NC && t >= dd) ofs[t] += v;
                __syncthreads();
            }
            if (t < NC) cnt[t] = ofs[t];
            __syncthreads();
            for (int r = 0; r < 32; ++r) {
                const int i = r * 256 + t;
                const int c = cellb[i];                        // cached cell
                const int pos = atomicAdd(&cnt[c], 1);
                qSorted[(size_t)b * N2 + pos] = b * N2 + i;    // global q idx
            }
            if (t <= NC) qCellStart[b * NCP + t] = ofs[t];
        }
        return;
    }

    // ------------------------------ GEMM path -------------------------------
    const int L  = (bx & 7) * 80 + (bx >> 3);   // bijective XCD swizzle (640=8*80)
    const bool g2 = L >= 128;
    const int ll  = g2 ? L - 128 : L;
    const int mb  = ll >> 1;
    const int nbi = ll & 1;

    const float* Fsrc        = g2 ? f2 : f1;
    const unsigned short* Wt = g2 ? Wt2 : Wt1;
    const float* bias        = g2 ? b2 : b1;
    unsigned short* Hb       = g2 ? h2b : h1b;
    float* sum               = sums + (g2 ? 512 : 0);
    float* sumsq             = sum + 256;
    const int row0 = mb * 128;
    const int n0   = nbi * 128;

    const int wave = t >> 6;
    const int lane = t & 63;
    const int wm   = (wave & 1) * 64;
    const int wn   = (wave >> 1) * 64;
    const int ml   = lane & 15;
    const int q    = lane >> 4;

    auto stageB = [&](int kt, int buf) {
        #pragma unroll
        for (int r = 0; r < 2; ++r) {
            const int e   = r * 2048 + t * 8;
            const int row = e >> 5;
            const int kk  = e & 31;
            async16(Wt + (size_t)(n0 + row) * 256 + kt * 32 + kk,
                    (unsigned short*)Bs[buf] + e);
        }
    };
    // A fragment source: lane needs rows wm+mt*16+ml, k = kt*32+q*8 .. +7 (f32)
    auto loadA = [&](int kt, float4 (&dst)[8]) {
        #pragma unroll
        for (int mt = 0; mt < 4; ++mt) {
            const float4* ap = (const float4*)Fsrc
                             + (size_t)(row0 + wm + mt * 16 + ml) * 64 + kt * 8 + q * 2;
            dst[2 * mt]     = ap[0];
            dst[2 * mt + 1] = ap[1];
        }
    };
    auto cvtA = [&](const float4 (&src)[8], bf16x8 (&af)[4]) {
        #pragma unroll
        for (int mt = 0; mt < 4; ++mt) {
            u16x8 v;
            v[0] = f2bf(src[2 * mt].x);     v[1] = f2bf(src[2 * mt].y);
            v[2] = f2bf(src[2 * mt].z);     v[3] = f2bf(src[2 * mt].w);
            v[4] = f2bf(src[2 * mt + 1].x); v[5] = f2bf(src[2 * mt + 1].y);
            v[6] = f2bf(src[2 * mt + 1].z); v[7] = f2bf(src[2 * mt + 1].w);
            af[mt] = *(const bf16x8*)&v;
        }
    };

    f32x4 acc[4][4] = {};
    float4 arP[8], arQ[8];                // ping-pong A reg stage (static names)

    stageB(0, 0);
    loadA(0, arP);
    __syncthreads();                      // prologue drain: B(0)+A(0)

#define GEMM_STEP(KT, CURA, NXTA, CBUF)                                        \
    {                                                                          \
        if ((KT) < 7) stageB((KT) + 1, (CBUF) ^ 1);    /* issue early */       \
        if ((KT) < 7) loadA((KT) + 1, NXTA);           /* issue early */       \
        bf16x8 af[4];                                                          \
        cvtA(CURA, af);                                                        \
        bf16x8 bfr[4];                                                         \
        _Pragma("unroll")                                                      \
        for (int nt = 0; nt < 4; ++nt)                                         \
            bfr[nt] = *(const bf16x8*)&Bs[CBUF][(wn + nt * 16 + ml) * 32 + q * 8]; \
        _Pragma("unroll")                                                      \
        for (int mt = 0; mt < 4; ++mt)                                         \
            _Pragma("unroll")                                                  \
            for (int nt = 0; nt < 4; ++nt)                                     \
                acc[mt][nt] = __builtin_amdgcn_mfma_f32_16x16x32_bf16(         \
                    af[mt], bfr[nt], acc[mt][nt], 0, 0, 0);                    \
        if ((KT) < 7) __syncthreads();    /* drain has full compute as cover */\
    }

    GEMM_STEP(0, arP, arQ, 0)
    GEMM_STEP(1, arQ, arP, 1)
    GEMM_STEP(2, arP, arQ, 0)
    GEMM_STEP(3, arQ, arP, 1)
    GEMM_STEP(4, arP, arQ, 0)
    GEMM_STEP(5, arQ, arP, 1)
    GEMM_STEP(6, arP, arQ, 0)
    GEMM_STEP(7, arQ, arP, 1)
#undef GEMM_STEP

    // ---- epilogue: bias, bf16 store, BN partial sums (identical to R7) ----
    float bv[4], psum[4], psq[4];
    #pragma unroll
    for (int nt = 0; nt < 4; ++nt) {
        bv[nt] = bias[n0 + wn + nt * 16 + ml];
        psum[nt] = 0.0f; psq[nt] = 0.0f;
    }
    #pragma unroll
    for (int mt = 0; mt < 4; ++mt)
        #pragma unroll
        for (int nt = 0; nt < 4; ++nt)
            #pragma unroll
            for (int r = 0; r < 4; ++r) {
                const float v = acc[mt][nt][r] + bv[nt];
                const int grow = row0 + wm + mt * 16 + q * 4 + r;
                Hb[(size_t)grow * 256 + n0 + wn + nt * 16 + ml] = f2bf(v);
                psum[nt] += v;
                psq[nt]  = fmaf(v, v, psq[nt]);
            }
    #pragma unroll
    for (int nt = 0; nt < 4; ++nt) {
        psum[nt] += __shfl_xor(psum[nt], 16, 64);
        psum[nt] += __shfl_xor(psum[nt], 32, 64);
        psq[nt]  += __shfl_xor(psq[nt], 16, 64);
        psq[nt]  += __shfl_xor(psq[nt], 32, 64);
    }
    if (q == 0) {
        #pragma unroll
        for (int nt = 0; nt < 4; ++nt) {
            const int col = n0 + wn + nt * 16 + ml;
            atomicAdd(&sum[col],   psum[nt]);
            atomicAdd(&sumsq[col], psq[nt]);
        }
    }
}

// =============================================================================
// Dispatch 3: grid-pruned exact kNN + merge + BN-fold + interpolate + add + tail.
// (identical to R7 — passed at 161.8 µs)
// =============================================================================
__global__ __launch_bounds__(512) void fused_kernel(const float* __restrict__ p2,
                                                    const unsigned short* __restrict__ h1b,
                                                    const unsigned short* __restrict__ h2b,
                                                    const float* __restrict__ sums,
                                                    const float* __restrict__ g1,
                                                    const float* __restrict__ be1,
                                                    const float* __restrict__ g2,
                                                    const float* __restrict__ be2,
                                                    const float4* __restrict__ gridPts,
                                                    const int* __restrict__ cellStart,
                                                    const int* __restrict__ qSorted,
                                                    const int* __restrict__ qCellStart,
                                                    float* __restrict__ out) {
    __shared__ float ssl[4][256];      // 4 KB  (s1,t1,s2,t2)
    __shared__ int   cst[NCP];         // cellStart slice for this batch
    __shared__ float pdl[8][64][3];    // 6 KB
    __shared__ int   pil[8][64][3];    // 6 KB
    __shared__ float qdl[64][3];       // running best distances per query
    __shared__ int   qjl[64][3];       // running best indices (in-batch)
    __shared__ float wql[64][3];
    __shared__ int   jql[64][3];
    __shared__ int   qidl[64];
    __shared__ float qpx[64], qpy[64], qpz[64];

    const int t    = threadIdx.x;
    const int bx   = blockIdx.x;
    const int b    = bx / NC;
    const int cid  = bx - b * NC;      // bucket home cell (uniform)
    const int ccx  = cid % 6;
    const int ccy  = (cid / 6) % 6;
    const int ccz  = cid / 36;
    const int wave = t >> 6;
    const int lane = t & 63;

    // ---- BN fold + cellStart staging ----
    if (t < 256) {
        const float m1 = sums[t] * (1.0f / (float)NTOT1);
        const float v1 = sums[256 + t] * (1.0f / (float)NTOT1) - m1 * m1;
        const float s1 = g1[t] * rsqrtf(v1 + BN_EPS);
        ssl[0][t] = s1;
        ssl[1][t] = be1[t] - m1 * s1;
        const float m2 = sums[512 + t] * (1.0f / (float)NTOT2);
        const float v2 = sums[768 + t] * (1.0f / (float)NTOT2) - m2 * m2;
        const float s2 = g2[t] * rsqrtf(v2 + BN_EPS);
        ssl[2][t] = s2;
        ssl[3][t] = be2[t] - m2 * s2;
    }
    if (t < NCP) cst[t] = cellStart[b * NCP + t];

    const int qs = qCellStart[b * NCP + cid];
    const int qe = qCellStart[b * NCP + cid + 1];
    const float4* __restrict__ gp = gridPts + (size_t)b * N1;

    for (int q0 = qs; q0 < qe; q0 += 64) {
        const int nqc = min(64, qe - q0);
        __syncthreads();   // (1st iter: ssl/cst ready; later: qidl/jql reuse safe)
        if (t < 64) {
            int qid = 0;
            float x = 1e30f, y = 1e30f, z = 1e30f;
            if (t < nqc) {
                qid = qSorted[(size_t)b * N2 + q0 + t];
                const size_t pb = (size_t)qid * 3;
                x = p2[pb]; y = p2[pb + 1]; z = p2[pb + 2];
            }
            qidl[t] = qid;
            qpx[t] = x; qpy[t] = y; qpz[t] = z;
        }
        __syncthreads();

        const float qx = qpx[lane], qy = qpy[lane], qz = qpz[lane];

        // scan chebyshev box (R==1) or shell (R>1); wave-uniform control flow
        auto scan_box = [&](int R, float& d0, float& d1, float& d2,
                            int& i0, int& i1, int& i2) {
            const int dim  = 2 * R + 1;
            const int dim2 = dim * dim;
            const int nsl  = dim2 * dim;
            for (int sl = wave; sl < nsl; sl += 8) {
                int lz = sl / dim2;
                const int rem = sl - lz * dim2;
                int ly = rem / dim;
                int lx = rem - ly * dim;
                lx -= R; ly -= R; lz -= R;
                if (R > 1) {
                    const int ax = lx < 0 ? -lx : lx;
                    const int ay = ly < 0 ? -ly : ly;
                    const int az = lz < 0 ? -lz : lz;
                    int ch = ax > ay ? ax : ay;
                    ch = ch > az ? ch : az;
                    if (ch < R) continue;              // interior already scanned
                }
                const int gx = ccx + lx;
                const int gy = ccy + ly;
                const int gz = ccz + lz;
                if ((unsigned)gx >= 6u || (unsigned)gy >= 6u || (unsigned)gz >= 6u)
                    continue;
                const int cc = (gz * 6 + gy) * 6 + gx;
                const int s = __builtin_amdgcn_readfirstlane(cst[cc]);
                const int e = __builtin_amdgcn_readfirstlane(cst[cc + 1]);
                for (int j = s; j < e; ++j) {
                    const float4 p = gp[j];            // uniform (broadcast) load
                    const float dx = p.x - qx;
                    const float dy = p.y - qy;
                    const float dz = p.z - qz;
                    float d = dx * dx;
                    d = fmaf(dy, dy, d);
                    d = fmaf(dz, dz, d);
                    ins3m(d, __float_as_int(p.w), d0, d1, d2, i0, i1, i2);
                }
            }
        };

        // merge 8 partials into running best, check exactness bound; returns
        // count of unfinished queries (block-uniform).
        auto merge_check = [&](int R) -> int {
            int notdone = 0;
            if (t < 64) {
                float m0, m1, m2;
                int a0, a1, a2;
                if (R == 1) { m0 = m1 = m2 = 1e30f; a0 = a1 = a2 = 0; }
                else {
                    m0 = qdl[t][0]; m1 = qdl[t][1]; m2 = qdl[t][2];
                    a0 = qjl[t][0]; a1 = qjl[t][1]; a2 = qjl[t][2];
                }
                #pragma unroll
                for (int s = 0; s < 8; ++s)
                    #pragma unroll
                    for (int k = 0; k < 3; ++k)
                        ins3m(pdl[s][t][k], pil[s][t][k], m0, m1, m2, a0, a1, a2);
                qdl[t][0] = m0; qdl[t][1] = m1; qdl[t][2] = m2;
                qjl[t][0] = a0; qjl[t][1] = a1; qjl[t][2] = a2;
                if (t < nqc) {
                    float dmin = 1e30f;
                    {
                        const int lo = ccx - R, hi = ccx + R;
                        if (lo > 0) dmin = fminf(dmin, qpx[t] - (float)lo * GH);
                        if (hi < 5) dmin = fminf(dmin, (float)(hi + 1) * GH - qpx[t]);
                    }
                    {
                        const int lo = ccy - R, hi = ccy + R;
                        if (lo > 0) dmin = fminf(dmin, qpy[t] - (float)lo * GH);
                        if (hi < 5) dmin = fminf(dmin, (float)(hi + 1) * GH - qpy[t]);
                    }
                    {
                        const int lo = ccz - R, hi = ccz + R;
                        if (lo > 0) dmin = fminf(dmin, qpz[t] - (float)lo * GH);
                        if (hi < 5) dmin = fminf(dmin, (float)(hi + 1) * GH - qpz[t]);
                    }
                    if (m2 > dmin * dmin * 0.9999f) notdone = 1;
                }
            }
            return __syncthreads_count(notdone);
        };

        // ---- ring 1 (hot path, const-folded dim=3) ----
        {
            float d0 = 1e30f, d1 = 1e30f, d2 = 1e30f;
            int i0 = 0, i1 = 0, i2 = 0;
            scan_box(1, d0, d1, d2, i0, i1, i2);
            pdl[wave][lane][0] = d0; pdl[wave][lane][1] = d1; pdl[wave][lane][2] = d2;
            pil[wave][lane][0] = i0; pil[wave][lane][1] = i1; pil[wave][lane][2] = i2;
        }
        __syncthreads();
        int need = merge_check(1);
        // ---- rare expansion rings; shell points can't beat a satisfied d2,
        //      so no per-lane masking needed. R=6 covers the whole domain. ----
        for (int R = 2; need != 0 && R <= 6; ++R) {
            float d0 = 1e30f, d1 = 1e30f, d2 = 1e30f;
            int i0 = 0, i1 = 0, i2 = 0;
            scan_box(R, d0, d1, d2, i0, i1, i2);
            pdl[wave][lane][0] = d0; pdl[wave][lane][1] = d1; pdl[wave][lane][2] = d2;
            pil[wave][lane][0] = i0; pil[wave][lane][1] = i1; pil[wave][lane][2] = i2;
            __syncthreads();
            need = merge_check(R);
        }

        // ---- weights (reference formula) ----
        if (t < nqc) {
            const float w0 = 1.0f / fmaxf(qdl[t][0], 1e-16f);
            const float w1 = 1.0f / fmaxf(qdl[t][1], 1e-16f);
            const float w2 = 1.0f / fmaxf(qdl[t][2], 1e-16f);
            const float inv = 1.0f / (w0 + w1 + w2);
            wql[t][0] = w0 * inv; wql[t][1] = w1 * inv; wql[t][2] = w2 * inv;
            jql[t][0] = b * N1 + qjl[t][0];
            jql[t][1] = b * N1 + qjl[t][1];
            jql[t][2] = b * N1 + qjl[t][2];
        }
        __syncthreads();

        // ---- interpolate + BN-apply + add; (feature-pair x strided query) ----
        {
            const int fp = t & 127;
            const int f0 = fp * 2;
            const float s1a = ssl[0][f0],     t1a = ssl[1][f0];
            const float s2a = ssl[2][f0],     t2a = ssl[3][f0];
            const float s1b = ssl[0][f0 + 1], t1b = ssl[1][f0 + 1];
            const float s2b = ssl[2][f0 + 1], t2b = ssl[3][f0 + 1];
            for (int v = t >> 7; v < nqc; v += 4) {
                const int qid = qidl[v];
                const int   j0 = jql[v][0], j1 = jql[v][1], j2 = jql[v][2];
                const float w0 = wql[v][0], w1 = wql[v][1], w2 = wql[v][2];

                const unsigned u0 = *(const unsigned*)(h1b + (size_t)j0 * F + f0);
                const unsigned u1 = *(const unsigned*)(h1b + (size_t)j1 * F + f0);
                const unsigned u2 = *(const unsigned*)(h1b + (size_t)j2 * F + f0);
                const unsigned uh = *(const unsigned*)(h2b + (size_t)qid * F + f0);

                float alo = w0 * bflo(u0);
                alo = fmaf(w1, bflo(u1), alo);
                alo = fmaf(w2, bflo(u2), alo);
                float ahi = w0 * bfhi(u0);
                ahi = fmaf(w1, bfhi(u1), ahi);
                ahi = fmaf(w2, bfhi(u2), ahi);

                float2 o;
                o.x = fmaf(alo, s1a, t1a) + fmaf(bflo(uh), s2a, t2a);
                o.y = fmaf(ahi, s1b, t1b) + fmaf(bfhi(uh), s2b, t2b);
                *(float2*)(out + (size_t)qid * F + f0) = o;
            }
        }
    }

    // ---- passthrough tail (152 elems per block, 864*152 >= 131072) ----
    if (t < 152) {
        const int tid = bx * 152 + t;
        if (tid < NTOT2 * 3) {
            out[(size_t)NTOT2 * F + tid] = p2[tid];
        } else if (tid < NTOT2 * 3 + NTOT2) {
            const int e = tid - NTOT2 * 3;
            out[(size_t)NTOT2 * F + NTOT2 * 3 + e] = (float)(e >> 13);
        }
    }
}

// -----------------------------------------------------------------------------
extern "C" void kernel_launch(void* const* d_in, const int* in_sizes, int n_in,
                              void* d_out, int out_size, void* d_ws, size_t ws_size,
                              hipStream_t stream) {
    const float* f1  = (const float*)d_in[0];
    const float* p1  = (const float*)d_in[1];
    const float* f2  = (const float*)d_in[3];
    const float* p2  = (const float*)d_in[4];
    const float* W1  = (const float*)d_in[6];
    const float* b1  = (const float*)d_in[7];
    const float* g1  = (const float*)d_in[8];
    const float* be1 = (const float*)d_in[9];
    const float* W2  = (const float*)d_in[10];
    const float* b2  = (const float*)d_in[11];
    const float* g2  = (const float*)d_in[12];
    const float* be2 = (const float*)d_in[13];

    char* ws = (char*)d_ws;
    unsigned short* Wt1   = (unsigned short*)(ws);               //    131,072
    unsigned short* Wt2   = (unsigned short*)(ws + 131072);      //    131,072
    unsigned short* h1b   = (unsigned short*)(ws + 262144);      //  4,194,304
    unsigned short* h2b   = (unsigned short*)(ws + 4456448);     // 16,777,216
    float*          sums  = (float*)(ws + 21233664);             //      4,096
    float4*         gridPts    = (float4*)(ws + 21237760);       //    131,072
    int*            cellStart  = (int*)(ws + 21368832);          //      3,584
    int*            qSorted    = (int*)(ws + 21372416);          //    131,072
    int*            qCellStart = (int*)(ws + 21503488);          //      3,584
    float*          out   = (float*)d_out;

    prep_kernel<<<33, 256, 0, stream>>>(W1, W2, Wt1, Wt2, sums);

    gemm_mfma_kernel<<<648, 256, 0, stream>>>(f1, f2, Wt1, Wt2, b1, b2, p1, p2,
                                              h1b, h2b, sums,
                                              gridPts, cellStart, qSorted, qCellStart);

    fused_kernel<<<864, 512, 0, stream>>>(p2, h1b, h2b, sums,
                                          g1, be1, g2, be2,
                                          gridPts, cellStart, qSorted, qCellStart,
                                          out);
}

// Round 9
// 160.130 us; speedup vs baseline: 1.0580x; 1.0580x over previous
//
#include <hip/hip_runtime.h>
#include <math.h>

#define BATCH   4
#define N1      2048
#define N2      8192
#define F       256
#define NTOT1   (BATCH * N1)    // 8192
#define NTOT2   (BATCH * N2)    // 32768
#define BN_EPS  1e-5f

// kNN acceleration grid: 6x6x6 cells over [0,1)^3, ~9.5 pts/cell
#define GR      6
#define NC      216             // GR^3
#define NCP     (NC + 1)        // 217
#define GH      (1.0f / 6.0f)

typedef __attribute__((ext_vector_type(8))) short bf16x8;
typedef __attribute__((ext_vector_type(8))) unsigned short u16x8;
typedef __attribute__((ext_vector_type(4))) float f32x4;

// ---------------- helpers ----------------------------------------------------
__device__ __forceinline__ unsigned short f2bf(float f) {   // RNE f32->bf16
    unsigned u = __float_as_uint(f);
    unsigned r = (u + 0x7fffu + ((u >> 16) & 1u)) >> 16;
    return (unsigned short)r;
}
__device__ __forceinline__ float bflo(unsigned u) {         // low bf16 of pair
    return __uint_as_float(u << 16);
}
__device__ __forceinline__ float bfhi(unsigned u) {         // high bf16 of pair
    return __uint_as_float(u & 0xffff0000u);
}
__device__ __forceinline__ void async16(const void* g, void* l) {
    __builtin_amdgcn_global_load_lds(
        (const __attribute__((address_space(1))) unsigned int*)g,
        (__attribute__((address_space(3))) unsigned int*)l, 16, 0, 0);
}

// branchless top-3 insert, med3 form. Invariant d0<=d1<=d2.
// Strict < == first-occurrence tie-break.
__device__ __forceinline__ void ins3m(float d, int j,
                                      float& d0, float& d1, float& d2,
                                      int& j0, int& j1, int& j2) {
    const bool c0 = d < d0;
    const bool c1 = d < d1;
    const bool c2 = d < d2;
    const float nd1 = __builtin_amdgcn_fmed3f(d, d0, d1);
    const float nd2 = __builtin_amdgcn_fmed3f(d, d1, d2);
    d0 = fminf(d, d0);
    d1 = nd1;
    d2 = nd2;
    j2 = c1 ? j1 : (c2 ? j : j2);
    j1 = c0 ? j0 : (c1 ? j : j1);
    j0 = c0 ? j  : j0;
}

__device__ __forceinline__ int clamp6(int c) { return c < 0 ? 0 : (c > 5 ? 5 : c); }
__device__ __forceinline__ int cell_of(float x, float y, float z) {
    const int cx = clamp6((int)(x * 6.0f));
    const int cy = clamp6((int)(y * 6.0f));
    const int cz = clamp6((int)(z * 6.0f));
    return (cz * 6 + cy) * 6 + cx;
}

// =============================================================================
// Dispatch 1: prep — W->bf16 transposed + zero stats. grid = 33 blocks.
// =============================================================================
__global__ __launch_bounds__(256) void prep_kernel(const float* __restrict__ W1,
                                                   const float* __restrict__ W2,
                                                   unsigned short* __restrict__ Wt1,
                                                   unsigned short* __restrict__ Wt2,
                                                   float* __restrict__ sums) {
    const int bx = blockIdx.x;
    const int t  = threadIdx.x;

    if (bx < 32) {                        // W transpose+convert
        __shared__ float tile[64][65];
        const bool second = bx >= 16;
        const int bl = second ? bx - 16 : bx;
        const float* W = second ? W2 : W1;
        unsigned short* Wt = second ? Wt2 : Wt1;
        const int gx0 = (bl & 3) * 64;    // n block
        const int gy0 = (bl >> 2) * 64;   // k block
        const int tx = t & 63;
        const int ty = t >> 6;
        #pragma unroll
        for (int j = 0; j < 16; ++j) {
            const int row = ty * 16 + j;
            tile[row][tx] = W[(size_t)(gy0 + row) * 256 + gx0 + tx];
        }
        __syncthreads();
        #pragma unroll
        for (int j = 0; j < 16; ++j) {
            const int row = ty * 16 + j;
            Wt[(size_t)(gx0 + row) * 256 + gy0 + tx] = f2bf(tile[tx][row]);
        }
    } else {                              // zero sums (before gemm's atomics)
        #pragma unroll
        for (int i = 0; i < 4; ++i) sums[t + 256 * i] = 0.0f;
    }
}

// =============================================================================
// Dispatch 2: both GEMMs (bx<640) + CONCURRENT binning blocks (bx 640..647).
// GEMM = R7 structure (coalesced A f32->reg->cvt->ds_write, async16 B) with
// ONE change: BK=64 (4 slabs, 8 barrier-drains instead of 16) + XOR-swizzled
// LDS (off ^= (row&7)<<3 shorts; B swizzled via pre-swizzled global source,
// linear LDS dest). MFMA inputs & accumulation order bit-identical to R7.
// =============================================================================
__global__ __launch_bounds__(256) void gemm_mfma_kernel(const float* __restrict__ f1,
                                                        const float* __restrict__ f2,
                                                        const unsigned short* __restrict__ Wt1,
                                                        const unsigned short* __restrict__ Wt2,
                                                        const float* __restrict__ b1,
                                                        const float* __restrict__ b2,
                                                        const float* __restrict__ p1,
                                                        const float* __restrict__ p2,
                                                        unsigned short* __restrict__ h1b,
                                                        unsigned short* __restrict__ h2b,
                                                        float* __restrict__ sums,
                                                        float4* __restrict__ gridPts,
                                                        int* __restrict__ cellStart,
                                                        int* __restrict__ qSorted,
                                                        int* __restrict__ qCellStart) {
    __shared__ unsigned short As[128 * 64];   // 16 KB
    __shared__ unsigned short Bs[128 * 64];   // 16 KB

    const int bx = blockIdx.x;
    const int t  = threadIdx.x;

    if (bx >= 640) {                      // ---- binning blocks (for fused) ----
        __shared__ int cnt[NC];
        __shared__ int ofs[NCP];
        __shared__ unsigned char cellb[N2];   // 8 KB query-cell cache
        const int bb = bx - 640;
        if (bb < 4) {                     // bin points of batch bb into 6^3 grid
            const int b = bb;
            if (t < NC) cnt[t] = 0;
            __syncthreads();
            int   myc[8];
            float mx[8], my[8], mz[8];
            #pragma unroll
            for (int r = 0; r < 8; ++r) {
                const int i = r * 256 + t;
                const size_t base = (size_t)(b * N1 + i) * 3;
                mx[r] = p1[base]; my[r] = p1[base + 1]; mz[r] = p1[base + 2];
                myc[r] = cell_of(mx[r], my[r], mz[r]);
                atomicAdd(&cnt[myc[r]], 1);
            }
            __syncthreads();
            if (t <= NC) ofs[t] = (t == 0) ? 0 : cnt[t - 1];   // exclusive init
            __syncthreads();
            for (int dd = 1; dd < NCP; dd <<= 1) {             // Hillis-Steele
                int v = 0;
                if (t <= NC && t >= dd) v = ofs[t - dd];
                __syncthreads();
                if (t <= NC && t >= dd) ofs[t] += v;
                __syncthreads();
            }
            if (t < NC) cnt[t] = ofs[t];                       // cursors
            __syncthreads();
            #pragma unroll
            for (int r = 0; r < 8; ++r) {
                const int i = r * 256 + t;
                const int pos = atomicAdd(&cnt[myc[r]], 1);
                float4 rec;
                rec.x = mx[r]; rec.y = my[r]; rec.z = mz[r];
                rec.w = __int_as_float(i);                     // in-batch idx
                gridPts[(size_t)b * N1 + pos] = rec;
            }
            if (t <= NC) cellStart[b * NCP + t] = ofs[t];
        } else {                          // bin queries of batch bb-4
            const int b = bb - 4;
            if (t < NC) cnt[t] = 0;
            __syncthreads();
            for (int r = 0; r < 32; ++r) {
                const int i = r * 256 + t;
                const size_t base = (size_t)(b * N2 + i) * 3;
                const int c = cell_of(p2[base], p2[base + 1], p2[base + 2]);
                cellb[i] = (unsigned char)c;
                atomicAdd(&cnt[c], 1);
            }
            __syncthreads();
            if (t <= NC) ofs[t] = (t == 0) ? 0 : cnt[t - 1];
            __syncthreads();
            for (int dd = 1; dd < NCP; dd <<= 1) {
                int v = 0;
                if (t <= NC && t >= dd) v = ofs[t - dd];
                __syncthreads();
                if (t <= NC && t >= dd) ofs[t] += v;
                __syncthreads();
            }
            if (t < NC) cnt[t] = ofs[t];
            __syncthreads();
            for (int r = 0; r < 32; ++r) {
                const int i = r * 256 + t;
                const int c = cellb[i];                        // cached cell
                const int pos = atomicAdd(&cnt[c], 1);
                qSorted[(size_t)b * N2 + pos] = b * N2 + i;    // global q idx
            }
            if (t <= NC) qCellStart[b * NCP + t] = ofs[t];
        }
        return;
    }

    // ------------------------------ GEMM path -------------------------------
    const int L  = (bx & 7) * 80 + (bx >> 3);   // bijective XCD swizzle (640=8*80)
    const bool g2 = L >= 128;
    const int ll  = g2 ? L - 128 : L;
    const int mb  = ll >> 1;
    const int nbi = ll & 1;

    const float* Fsrc        = g2 ? f2 : f1;
    const unsigned short* Wt = g2 ? Wt2 : Wt1;
    const float* bias        = g2 ? b2 : b1;
    unsigned short* Hb       = g2 ? h2b : h1b;
    float* sum               = sums + (g2 ? 512 : 0);
    float* sumsq             = sum + 256;
    const int row0 = mb * 128;
    const int n0   = nbi * 128;

    const int wave = t >> 6;
    const int lane = t & 63;
    const int wm   = (wave & 1) * 64;
    const int wn   = (wave >> 1) * 64;
    const int ml   = lane & 15;
    const int q    = lane >> 4;

    // A-staging: 128 rows x 64 k (f32) per slab; thread handles 4 8-float
    // chunks: pi = i*256+t, row = pi>>3, q2 = pi&7. Coalesced (consec t ->
    // consec 32 B). LDS write XOR-swizzled: off = q2*8 ^ ((row&7)<<3) shorts.
    float4 arA[4], arB[4];
    auto loadA = [&](int s) {
        #pragma unroll
        for (int i = 0; i < 4; ++i) {
            const int pi  = i * 256 + t;
            const int row = pi >> 3;
            const int q2  = pi & 7;
            const float4* src = (const float4*)Fsrc
                              + (size_t)(row0 + row) * 64 + s * 16 + q2 * 2;
            arA[i] = src[0];
            arB[i] = src[1];
        }
    };
    auto writeA = [&]() {
        #pragma unroll
        for (int i = 0; i < 4; ++i) {
            const int pi  = i * 256 + t;
            const int row = pi >> 3;
            const int q2  = pi & 7;
            u16x8 v;
            v[0] = f2bf(arA[i].x); v[1] = f2bf(arA[i].y);
            v[2] = f2bf(arA[i].z); v[3] = f2bf(arA[i].w);
            v[4] = f2bf(arB[i].x); v[5] = f2bf(arB[i].y);
            v[6] = f2bf(arB[i].z); v[7] = f2bf(arB[i].w);
            *(u16x8*)&As[row * 64 + ((q2 * 8) ^ ((row & 7) << 3))] = v;
        }
    };
    // B-staging: linear LDS dest (async16 requirement), swizzle applied on
    // the per-lane GLOBAL source address (same involution as the read side).
    auto stageB = [&](int s) {
        #pragma unroll
        for (int r = 0; r < 4; ++r) {
            const int e   = r * 2048 + t * 8;   // shorts
            const int row = e >> 6;
            const int kk  = e & 63;
            const int ks  = kk ^ ((row & 7) << 3);
            async16(Wt + (size_t)(n0 + row) * 256 + s * 64 + ks,
                    (unsigned short*)Bs + e);
        }
    };

    f32x4 acc[4][4] = {};

    // prologue: fill As/Bs for slab 0, prefetch A(1)
    loadA(0);
    stageB(0);
    writeA();
    loadA(1);
    __syncthreads();                      // drain ds_write + async B(0)

    const int rsw = (ml & 7) << 3;        // read-side swizzle (row&7 == ml&7)
    #pragma unroll
    for (int s = 0; s < 4; ++s) {
        #pragma unroll
        for (int h = 0; h < 2; ++h) {     // k = s*64 + h*32 (ascending, == R7)
            const int ko = (h * 32 + q * 8) ^ rsw;
            bf16x8 af[4], bfr[4];
            #pragma unroll
            for (int mt = 0; mt < 4; ++mt)
                af[mt] = *(const bf16x8*)&As[(wm + mt * 16 + ml) * 64 + ko];
            #pragma unroll
            for (int nt = 0; nt < 4; ++nt)
                bfr[nt] = *(const bf16x8*)&Bs[(wn + nt * 16 + ml) * 64 + ko];
            #pragma unroll
            for (int mt = 0; mt < 4; ++mt)
                #pragma unroll
                for (int nt = 0; nt < 4; ++nt)
                    acc[mt][nt] = __builtin_amdgcn_mfma_f32_16x16x32_bf16(af[mt], bfr[nt],
                                                                          acc[mt][nt], 0, 0, 0);
        }
        if (s < 3) {
            __syncthreads();              // all waves done reading As/Bs
            stageB(s + 1);
            writeA();                     // regs hold slab s+1 data
            if (s < 2) loadA(s + 2);      // prefetch
            __syncthreads();              // drain writes + async
        }
    }

    // ---- epilogue: bias, bf16 store, BN partial sums (identical to R7) ----
    float bv[4], psum[4], psq[4];
    #pragma unroll
    for (int nt = 0; nt < 4; ++nt) {
        bv[nt] = bias[n0 + wn + nt * 16 + ml];
        psum[nt] = 0.0f; psq[nt] = 0.0f;
    }
    #pragma unroll
    for (int mt = 0; mt < 4; ++mt)
        #pragma unroll
        for (int nt = 0; nt < 4; ++nt)
            #pragma unroll
            for (int r = 0; r < 4; ++r) {
                const float v = acc[mt][nt][r] + bv[nt];
                const int grow = row0 + wm + mt * 16 + q * 4 + r;
                Hb[(size_t)grow * 256 + n0 + wn + nt * 16 + ml] = f2bf(v);
                psum[nt] += v;
                psq[nt]  = fmaf(v, v, psq[nt]);
            }
    #pragma unroll
    for (int nt = 0; nt < 4; ++nt) {
        psum[nt] += __shfl_xor(psum[nt], 16, 64);
        psum[nt] += __shfl_xor(psum[nt], 32, 64);
        psq[nt]  += __shfl_xor(psq[nt], 16, 64);
        psq[nt]  += __shfl_xor(psq[nt], 32, 64);
    }
    if (q == 0) {
        #pragma unroll
        for (int nt = 0; nt < 4; ++nt) {
            const int col = n0 + wn + nt * 16 + ml;
            atomicAdd(&sum[col],   psum[nt]);
            atomicAdd(&sumsq[col], psq[nt]);
        }
    }
}

// =============================================================================
// Dispatch 3: grid-pruned exact kNN + merge + BN-fold + interpolate + add + tail.
// (identical to R7 — passed at 161.8 µs)
// =============================================================================
__global__ __launch_bounds__(512) void fused_kernel(const float* __restrict__ p2,
                                                    const unsigned short* __restrict__ h1b,
                                                    const unsigned short* __restrict__ h2b,
                                                    const float* __restrict__ sums,
                                                    const float* __restrict__ g1,
                                                    const float* __restrict__ be1,
                                                    const float* __restrict__ g2,
                                                    const float* __restrict__ be2,
                                                    const float4* __restrict__ gridPts,
                                                    const int* __restrict__ cellStart,
                                                    const int* __restrict__ qSorted,
                                                    const int* __restrict__ qCellStart,
                                                    float* __restrict__ out) {
    __shared__ float ssl[4][256];      // 4 KB  (s1,t1,s2,t2)
    __shared__ int   cst[NCP];         // cellStart slice for this batch
    __shared__ float pdl[8][64][3];    // 6 KB
    __shared__ int   pil[8][64][3];    // 6 KB
    __shared__ float qdl[64][3];       // running best distances per query
    __shared__ int   qjl[64][3];       // running best indices (in-batch)
    __shared__ float wql[64][3];
    __shared__ int   jql[64][3];
    __shared__ int   qidl[64];
    __shared__ float qpx[64], qpy[64], qpz[64];

    const int t    = threadIdx.x;
    const int bx   = blockIdx.x;
    const int b    = bx / NC;
    const int cid  = bx - b * NC;      // bucket home cell (uniform)
    const int ccx  = cid % 6;
    const int ccy  = (cid / 6) % 6;
    const int ccz  = cid / 36;
    const int wave = t >> 6;
    const int lane = t & 63;

    // ---- BN fold + cellStart staging ----
    if (t < 256) {
        const float m1 = sums[t] * (1.0f / (float)NTOT1);
        const float v1 = sums[256 + t] * (1.0f / (float)NTOT1) - m1 * m1;
        const float s1 = g1[t] * rsqrtf(v1 + BN_EPS);
        ssl[0][t] = s1;
        ssl[1][t] = be1[t] - m1 * s1;
        const float m2 = sums[512 + t] * (1.0f / (float)NTOT2);
        const float v2 = sums[768 + t] * (1.0f / (float)NTOT2) - m2 * m2;
        const float s2 = g2[t] * rsqrtf(v2 + BN_EPS);
        ssl[2][t] = s2;
        ssl[3][t] = be2[t] - m2 * s2;
    }
    if (t < NCP) cst[t] = cellStart[b * NCP + t];

    const int qs = qCellStart[b * NCP + cid];
    const int qe = qCellStart[b * NCP + cid + 1];
    const float4* __restrict__ gp = gridPts + (size_t)b * N1;

    for (int q0 = qs; q0 < qe; q0 += 64) {
        const int nqc = min(64, qe - q0);
        __syncthreads();   // (1st iter: ssl/cst ready; later: qidl/jql reuse safe)
        if (t < 64) {
            int qid = 0;
            float x = 1e30f, y = 1e30f, z = 1e30f;
            if (t < nqc) {
                qid = qSorted[(size_t)b * N2 + q0 + t];
                const size_t pb = (size_t)qid * 3;
                x = p2[pb]; y = p2[pb + 1]; z = p2[pb + 2];
            }
            qidl[t] = qid;
            qpx[t] = x; qpy[t] = y; qpz[t] = z;
        }
        __syncthreads();

        const float qx = qpx[lane], qy = qpy[lane], qz = qpz[lane];

        // scan chebyshev box (R==1) or shell (R>1); wave-uniform control flow
        auto scan_box = [&](int R, float& d0, float& d1, float& d2,
                            int& i0, int& i1, int& i2) {
            const int dim  = 2 * R + 1;
            const int dim2 = dim * dim;
            const int nsl  = dim2 * dim;
            for (int sl = wave; sl < nsl; sl += 8) {
                int lz = sl / dim2;
                const int rem = sl - lz * dim2;
                int ly = rem / dim;
                int lx = rem - ly * dim;
                lx -= R; ly -= R; lz -= R;
                if (R > 1) {
                    const int ax = lx < 0 ? -lx : lx;
                    const int ay = ly < 0 ? -ly : ly;
                    const int az = lz < 0 ? -lz : lz;
                    int ch = ax > ay ? ax : ay;
                    ch = ch > az ? ch : az;
                    if (ch < R) continue;              // interior already scanned
                }
                const int gx = ccx + lx;
                const int gy = ccy + ly;
                const int gz = ccz + lz;
                if ((unsigned)gx >= 6u || (unsigned)gy >= 6u || (unsigned)gz >= 6u)
                    continue;
                const int cc = (gz * 6 + gy) * 6 + gx;
                const int s = __builtin_amdgcn_readfirstlane(cst[cc]);
                const int e = __builtin_amdgcn_readfirstlane(cst[cc + 1]);
                for (int j = s; j < e; ++j) {
                    const float4 p = gp[j];            // uniform (broadcast) load
                    const float dx = p.x - qx;
                    const float dy = p.y - qy;
                    const float dz = p.z - qz;
                    float d = dx * dx;
                    d = fmaf(dy, dy, d);
                    d = fmaf(dz, dz, d);
                    ins3m(d, __float_as_int(p.w), d0, d1, d2, i0, i1, i2);
                }
            }
        };

        // merge 8 partials into running best, check exactness bound; returns
        // count of unfinished queries (block-uniform).
        auto merge_check = [&](int R) -> int {
            int notdone = 0;
            if (t < 64) {
                float m0, m1, m2;
                int a0, a1, a2;
                if (R == 1) { m0 = m1 = m2 = 1e30f; a0 = a1 = a2 = 0; }
                else {
                    m0 = qdl[t][0]; m1 = qdl[t][1]; m2 = qdl[t][2];
                    a0 = qjl[t][0]; a1 = qjl[t][1]; a2 = qjl[t][2];
                }
                #pragma unroll
                for (int s = 0; s < 8; ++s)
                    #pragma unroll
                    for (int k = 0; k < 3; ++k)
                        ins3m(pdl[s][t][k], pil[s][t][k], m0, m1, m2, a0, a1, a2);
                qdl[t][0] = m0; qdl[t][1] = m1; qdl[t][2] = m2;
                qjl[t][0] = a0; qjl[t][1] = a1; qjl[t][2] = a2;
                if (t < nqc) {
                    float dmin = 1e30f;
                    {
                        const int lo = ccx - R, hi = ccx + R;
                        if (lo > 0) dmin = fminf(dmin, qpx[t] - (float)lo * GH);
                        if (hi < 5) dmin = fminf(dmin, (float)(hi + 1) * GH - qpx[t]);
                    }
                    {
                        const int lo = ccy - R, hi = ccy + R;
                        if (lo > 0) dmin = fminf(dmin, qpy[t] - (float)lo * GH);
                        if (hi < 5) dmin = fminf(dmin, (float)(hi + 1) * GH - qpy[t]);
                    }
                    {
                        const int lo = ccz - R, hi = ccz + R;
                        if (lo > 0) dmin = fminf(dmin, qpz[t] - (float)lo * GH);
                        if (hi < 5) dmin = fminf(dmin, (float)(hi + 1) * GH - qpz[t]);
                    }
                    if (m2 > dmin * dmin * 0.9999f) notdone = 1;
                }
            }
            return __syncthreads_count(notdone);
        };

        // ---- ring 1 (hot path, const-folded dim=3) ----
        {
            float d0 = 1e30f, d1 = 1e30f, d2 = 1e30f;
            int i0 = 0, i1 = 0, i2 = 0;
            scan_box(1, d0, d1, d2, i0, i1, i2);
            pdl[wave][lane][0] = d0; pdl[wave][lane][1] = d1; pdl[wave][lane][2] = d2;
            pil[wave][lane][0] = i0; pil[wave][lane][1] = i1; pil[wave][lane][2] = i2;
        }
        __syncthreads();
        int need = merge_check(1);
        // ---- rare expansion rings; shell points can't beat a satisfied d2,
        //      so no per-lane masking needed. R=6 covers the whole domain. ----
        for (int R = 2; need != 0 && R <= 6; ++R) {
            float d0 = 1e30f, d1 = 1e30f, d2 = 1e30f;
            int i0 = 0, i1 = 0, i2 = 0;
            scan_box(R, d0, d1, d2, i0, i1, i2);
            pdl[wave][lane][0] = d0; pdl[wave][lane][1] = d1; pdl[wave][lane][2] = d2;
            pil[wave][lane][0] = i0; pil[wave][lane][1] = i1; pil[wave][lane][2] = i2;
            __syncthreads();
            need = merge_check(R);
        }

        // ---- weights (reference formula) ----
        if (t < nqc) {
            const float w0 = 1.0f / fmaxf(qdl[t][0], 1e-16f);
            const float w1 = 1.0f / fmaxf(qdl[t][1], 1e-16f);
            const float w2 = 1.0f / fmaxf(qdl[t][2], 1e-16f);
            const float inv = 1.0f / (w0 + w1 + w2);
            wql[t][0] = w0 * inv; wql[t][1] = w1 * inv; wql[t][2] = w2 * inv;
            jql[t][0] = b * N1 + qjl[t][0];
            jql[t][1] = b * N1 + qjl[t][1];
            jql[t][2] = b * N1 + qjl[t][2];
        }
        __syncthreads();

        // ---- interpolate + BN-apply + add; (feature-pair x strided query) ----
        {
            const int fp = t & 127;
            const int f0 = fp * 2;
            const float s1a = ssl[0][f0],     t1a = ssl[1][f0];
            const float s2a = ssl[2][f0],     t2a = ssl[3][f0];
            const float s1b = ssl[0][f0 + 1], t1b = ssl[1][f0 + 1];
            const float s2b = ssl[2][f0 + 1], t2b = ssl[3][f0 + 1];
            for (int v = t >> 7; v < nqc; v += 4) {
                const int qid = qidl[v];
                const int   j0 = jql[v][0], j1 = jql[v][1], j2 = jql[v][2];
                const float w0 = wql[v][0], w1 = wql[v][1], w2 = wql[v][2];

                const unsigned u0 = *(const unsigned*)(h1b + (size_t)j0 * F + f0);
                const unsigned u1 = *(const unsigned*)(h1b + (size_t)j1 * F + f0);
                const unsigned u2 = *(const unsigned*)(h1b + (size_t)j2 * F + f0);
                const unsigned uh = *(const unsigned*)(h2b + (size_t)qid * F + f0);

                float alo = w0 * bflo(u0);
                alo = fmaf(w1, bflo(u1), alo);
                alo = fmaf(w2, bflo(u2), alo);
                float ahi = w0 * bfhi(u0);
                ahi = fmaf(w1, bfhi(u1), ahi);
                ahi = fmaf(w2, bfhi(u2), ahi);

                float2 o;
                o.x = fmaf(alo, s1a, t1a) + fmaf(bflo(uh), s2a, t2a);
                o.y = fmaf(ahi, s1b, t1b) + fmaf(bfhi(uh), s2b, t2b);
                *(float2*)(out + (size_t)qid * F + f0) = o;
            }
        }
    }

    // ---- passthrough tail (152 elems per block, 864*152 >= 131072) ----
    if (t < 152) {
        const int tid = bx * 152 + t;
        if (tid < NTOT2 * 3) {
            out[(size_t)NTOT2 * F + tid] = p2[tid];
        } else if (tid < NTOT2 * 3 + NTOT2) {
            const int e = tid - NTOT2 * 3;
            out[(size_t)NTOT2 * F + NTOT2 * 3 + e] = (float)(e >> 13);
        }
    }
}

// -----------------------------------------------------------------------------
extern "C" void kernel_launch(void* const* d_in, const int* in_sizes, int n_in,
                              void* d_out, int out_size, void* d_ws, size_t ws_size,
                              hipStream_t stream) {
    const float* f1  = (const float*)d_in[0];
    const float* p1  = (const float*)d_in[1];
    const float* f2  = (const float*)d_in[3];
    const float* p2  = (const float*)d_in[4];
    const float* W1  = (const float*)d_in[6];
    const float* b1  = (const float*)d_in[7];
    const float* g1  = (const float*)d_in[8];
    const float* be1 = (const float*)d_in[9];
    const float* W2  = (const float*)d_in[10];
    const float* b2  = (const float*)d_in[11];
    const float* g2  = (const float*)d_in[12];
    const float* be2 = (const float*)d_in[13];

    char* ws = (char*)d_ws;
    unsigned short* Wt1   = (unsigned short*)(ws);               //    131,072
    unsigned short* Wt2   = (unsigned short*)(ws + 131072);      //    131,072
    unsigned short* h1b   = (unsigned short*)(ws + 262144);      //  4,194,304
    unsigned short* h2b   = (unsigned short*)(ws + 4456448);     // 16,777,216
    float*          sums  = (float*)(ws + 21233664);             //      4,096
    float4*         gridPts    = (float4*)(ws + 21237760);       //    131,072
    int*            cellStart  = (int*)(ws + 21368832);          //      3,584
    int*            qSorted    = (int*)(ws + 21372416);          //    131,072
    int*            qCellStart = (int*)(ws + 21503488);          //      3,584
    float*          out   = (float*)d_out;

    prep_kernel<<<33, 256, 0, stream>>>(W1, W2, Wt1, Wt2, sums);

    gemm_mfma_kernel<<<648, 256, 0, stream>>>(f1, f2, Wt1, Wt2, b1, b2, p1, p2,
                                              h1b, h2b, sums,
                                              gridPts, cellStart, qSorted, qCellStart);

    fused_kernel<<<864, 512, 0, stream>>>(p2, h1b, h2b, sums,
                                          g1, be1, g2, be2,
                                          gridPts, cellStart, qSorted, qCellStart,
                                          out);
}